// Round 1
// baseline (215.049 us; speedup 1.0000x reference)
//
#include <hip/hip_runtime.h>
#include <cstddef>

typedef float f32x4 __attribute__((ext_vector_type(4)));
typedef short s16x8 __attribute__((ext_vector_type(8)));
typedef __bf16 bf16x8 __attribute__((ext_vector_type(8)));

#define NB 8
#define NS 1024
#define ND 768
#define NH 12
#define HD 64

__device__ __forceinline__ unsigned short f2bf(float f) {
  unsigned u = __builtin_bit_cast(unsigned, f);
  u += 0x7fffu + ((u >> 16) & 1u);
  return (unsigned short)(u >> 16);
}

__device__ __forceinline__ f32x4 mfma16(bf16x8 a, bf16x8 b, f32x4 c) {
  return __builtin_amdgcn_mfma_f32_16x16x32_bf16(a, b, c, 0, 0, 0);
}

__device__ __forceinline__ bf16x8 ld8(const unsigned short* p) {
  return *reinterpret_cast<const bf16x8*>(p);
}

// ---------------- pack kernels ----------------

__global__ __launch_bounds__(256) void cvt_f32_bf16(const float* __restrict__ in,
                                                    unsigned short* __restrict__ out) {
  int i = (blockIdx.x * 256 + threadIdx.x) * 4;
  float4 v = *reinterpret_cast<const float4*>(in + i);
  ushort4 o;
  o.x = f2bf(v.x); o.y = f2bf(v.y); o.z = f2bf(v.z); o.w = f2bf(v.w);
  *reinterpret_cast<ushort4*>(out + i) = o;
}

// in: fp32 [R][C] row-major  ->  out: bf16 [C][R]
__global__ __launch_bounds__(256) void transpose_cvt(const float* __restrict__ in,
                                                     unsigned short* __restrict__ out,
                                                     int R, int C) {
  __shared__ float tile[32][33];
  int c0 = blockIdx.x * 32, r0 = blockIdx.y * 32;
  int tx = threadIdx.x & 31, ty = threadIdx.x >> 5;  // 32 x 8
#pragma unroll
  for (int i = 0; i < 32; i += 8)
    tile[ty + i][tx] = in[(size_t)(r0 + ty + i) * C + c0 + tx];
  __syncthreads();
#pragma unroll
  for (int i = 0; i < 32; i += 8)
    out[(size_t)(c0 + ty + i) * R + r0 + tx] = f2bf(tile[tx][ty + i]);
}

// ---------------- GEMM mainloop (A:[M][K] bf16, Bt:[N][K] bf16) ----------------
// 128x128 tile, 4 waves (2x2), each wave 64x64 via 4x4 16x16x32 frags, BK=32.

#define LDK 40  // 32 + 8 pad (stride 80B -> 2-way LDS conflict, free)

__device__ __forceinline__ void gemm_mainloop(const unsigned short* __restrict__ A,
                                              const unsigned short* __restrict__ Bt,
                                              int K, int m0, int n0,
                                              unsigned short* As, unsigned short* Bs,
                                              f32x4 (&acc)[4][4]) {
  int tid = threadIdx.x;
  int lane = tid & 63, wid = tid >> 6;
  int wr = wid >> 1, wc = wid & 1;
  int srow = tid >> 1;          // 0..127
  int koff = (tid & 1) * 16;    // 0 or 16
  int ll = lane & 15, kg = (lane >> 4) * 8;

  for (int kt = 0; kt < K; kt += 32) {
    __syncthreads();
    *(s16x8*)&As[srow * LDK + koff] =
        *(const s16x8*)&A[(size_t)(m0 + srow) * K + kt + koff];
    *(s16x8*)&As[srow * LDK + koff + 8] =
        *(const s16x8*)&A[(size_t)(m0 + srow) * K + kt + koff + 8];
    *(s16x8*)&Bs[srow * LDK + koff] =
        *(const s16x8*)&Bt[(size_t)(n0 + srow) * K + kt + koff];
    *(s16x8*)&Bs[srow * LDK + koff + 8] =
        *(const s16x8*)&Bt[(size_t)(n0 + srow) * K + kt + koff + 8];
    __syncthreads();

    bf16x8 af[4], bfr[4];
#pragma unroll
    for (int m = 0; m < 4; m++) af[m] = ld8(&As[(wr * 64 + m * 16 + ll) * LDK + kg]);
#pragma unroll
    for (int n = 0; n < 4; n++) bfr[n] = ld8(&Bs[(wc * 64 + n * 16 + ll) * LDK + kg]);
#pragma unroll
    for (int m = 0; m < 4; m++)
#pragma unroll
      for (int n = 0; n < 4; n++) acc[m][n] = mfma16(af[m], bfr[n], acc[m][n]);
  }
}

// ---------------- QKV GEMM: x_bf16 @ WqkvT + bqkv -> q(scaled)/k/v [B,H,S,64] ----------------

__global__ __launch_bounds__(256) void qkv_gemm(const unsigned short* __restrict__ xbf,
                                                const unsigned short* __restrict__ WT,
                                                const float* __restrict__ bias,
                                                unsigned short* __restrict__ qw,
                                                unsigned short* __restrict__ kw,
                                                unsigned short* __restrict__ vw) {
  __shared__ __align__(16) unsigned short As[128 * LDK];
  __shared__ __align__(16) unsigned short Bs[128 * LDK];
  int m0 = blockIdx.y * 128, n0 = blockIdx.x * 128;
  f32x4 acc[4][4];
#pragma unroll
  for (int m = 0; m < 4; m++)
#pragma unroll
    for (int n = 0; n < 4; n++) acc[m][n] = (f32x4){0.f, 0.f, 0.f, 0.f};

  gemm_mainloop(xbf, WT, ND, m0, n0, As, Bs, acc);

  int tid = threadIdx.x, lane = tid & 63, wid = tid >> 6;
  int wr = wid >> 1, wc = wid & 1;
  int ll = lane & 15, lh = lane >> 4;
#pragma unroll
  for (int nf = 0; nf < 4; nf++) {
    int col = n0 + wc * 64 + nf * 16 + ll;
    float bv = bias[col];
    int which = col / ND;
    int w2 = col - which * ND;
    int h = w2 >> 6, d = w2 & 63;
#pragma unroll
    for (int mf = 0; mf < 4; mf++) {
#pragma unroll
      for (int r = 0; r < 4; r++) {
        int m = m0 + wr * 64 + mf * 16 + lh * 4 + r;
        int b = m >> 10, s = m & 1023;
        float v = acc[mf][nf][r] + bv;
        size_t idx = (((size_t)b * NH + h) * NS + s) * HD + d;
        if (which == 0)
          qw[idx] = f2bf(v * 0.125f);  // pre-scale by 1/sqrt(64), exact in bf16
        else if (which == 1)
          kw[idx] = f2bf(v);
        else
          vw[idx] = f2bf(v);
      }
    }
  }
}

// ---------------- flash attention: per (qtile, h, b) block ----------------

#define LKV 72  // 64 + 8 pad

__global__ __launch_bounds__(256) void attn_kernel(const unsigned short* __restrict__ qw,
                                                   const unsigned short* __restrict__ kw,
                                                   const unsigned short* __restrict__ vw,
                                                   unsigned short* __restrict__ attn_out) {
  int qt = blockIdx.x, h = blockIdx.y, b = blockIdx.z;
  __shared__ __align__(16) unsigned short Ks[64 * LKV];
  __shared__ __align__(16) unsigned short Vs[64 * LKV];  // transposed: [d][key]
  __shared__ __align__(16) unsigned short Ps[4][16 * LKV];

  int tid = threadIdx.x, lane = tid & 63, wid = tid >> 6;
  int ll = lane & 15, lh = lane >> 4, kg = lh * 8;
  int q0 = qt * 64;
  const size_t bh = ((size_t)b * NH + h) * NS * HD;

  // Q frags in registers (A-layout: row = lane&15, k = (lane>>4)*8+i)
  int qrow = q0 + wid * 16 + ll;
  bf16x8 qf0 = ld8(&qw[bh + (size_t)qrow * HD + kg]);
  bf16x8 qf1 = ld8(&qw[bh + (size_t)qrow * HD + 32 + kg]);

  f32x4 o[4];
#pragma unroll
  for (int n = 0; n < 4; n++) o[n] = (f32x4){0.f, 0.f, 0.f, 0.f};
  float m_r[4] = {-1e30f, -1e30f, -1e30f, -1e30f};
  float l_r[4] = {0.f, 0.f, 0.f, 0.f};

  int srow = tid >> 2;          // 0..63
  int soff = (tid & 3) * 16;    // 0,16,32,48

  for (int j0 = 0; j0 <= q0; j0 += 64) {
    __syncthreads();
    // stage K [key][d]
    *(s16x8*)&Ks[srow * LKV + soff] = *(const s16x8*)&kw[bh + (size_t)(j0 + srow) * HD + soff];
    *(s16x8*)&Ks[srow * LKV + soff + 8] =
        *(const s16x8*)&kw[bh + (size_t)(j0 + srow) * HD + soff + 8];
    // stage V transposed -> Vs[d][key]
    {
      s16x8 v0 = *(const s16x8*)&vw[bh + (size_t)(j0 + srow) * HD + soff];
      s16x8 v1 = *(const s16x8*)&vw[bh + (size_t)(j0 + srow) * HD + soff + 8];
#pragma unroll
      for (int e = 0; e < 8; e++) Vs[(soff + e) * LKV + srow] = (unsigned short)v0[e];
#pragma unroll
      for (int e = 0; e < 8; e++) Vs[(soff + 8 + e) * LKV + srow] = (unsigned short)v1[e];
    }
    __syncthreads();

    // S = Q K^T  (D-layout: row=(lane>>4)*4+r, col=n*16+(lane&15))
    f32x4 sa[4];
#pragma unroll
    for (int n = 0; n < 4; n++) sa[n] = (f32x4){0.f, 0.f, 0.f, 0.f};
#pragma unroll
    for (int n = 0; n < 4; n++) {
      bf16x8 kfa = ld8(&Ks[(n * 16 + ll) * LKV + kg]);
      bf16x8 kfb = ld8(&Ks[(n * 16 + ll) * LKV + 32 + kg]);
      sa[n] = mfma16(qf0, kfa, sa[n]);
      sa[n] = mfma16(qf1, kfb, sa[n]);
    }

    // causal mask on diagonal tile
    if (j0 == q0) {
      int rowb = wid * 16 + lh * 4;
#pragma unroll
      for (int n = 0; n < 4; n++) {
        int colg = n * 16 + ll;
#pragma unroll
        for (int r = 0; r < 4; r++)
          if (colg > rowb + r) sa[n][r] = -1e30f;
      }
    }

    // online softmax (row lives in 16 lanes of same lane>>4 group)
    float p[4][4];
#pragma unroll
    for (int r = 0; r < 4; r++) {
      float mx = fmaxf(fmaxf(sa[0][r], sa[1][r]), fmaxf(sa[2][r], sa[3][r]));
#pragma unroll
      for (int off = 8; off >= 1; off >>= 1) mx = fmaxf(mx, __shfl_xor(mx, off));
      float mnew = fmaxf(m_r[r], mx);
      float alpha = __expf(m_r[r] - mnew);
      float sm = 0.f;
#pragma unroll
      for (int n = 0; n < 4; n++) {
        p[n][r] = __expf(sa[n][r] - mnew);
        sm += p[n][r];
      }
#pragma unroll
      for (int off = 8; off >= 1; off >>= 1) sm += __shfl_xor(sm, off);
      l_r[r] = alpha * l_r[r] + sm;
      m_r[r] = mnew;
#pragma unroll
      for (int n = 0; n < 4; n++) o[n][r] *= alpha;
    }

    // P -> per-wave LDS (re-layout D-frag -> A-frag)
#pragma unroll
    for (int n = 0; n < 4; n++)
#pragma unroll
      for (int r = 0; r < 4; r++)
        Ps[wid][(lh * 4 + r) * LKV + n * 16 + ll] = f2bf(p[n][r]);
    __syncthreads();

    // O += P V   (A = P[16q][64k] from Ps, B = V[64k][64d] from Vs[d][key])
#pragma unroll
    for (int c = 0; c < 2; c++) {
      bf16x8 pf = ld8(&Ps[wid][ll * LKV + c * 32 + kg]);
#pragma unroll
      for (int n2 = 0; n2 < 4; n2++) {
        bf16x8 vf = ld8(&Vs[(n2 * 16 + ll) * LKV + c * 32 + kg]);
        o[n2] = mfma16(pf, vf, o[n2]);
      }
    }
  }

  // epilogue: normalize, store to [B,S,D] bf16 (merge heads)
#pragma unroll
  for (int n2 = 0; n2 < 4; n2++) {
#pragma unroll
    for (int r = 0; r < 4; r++) {
      int q = q0 + wid * 16 + lh * 4 + r;
      int d = n2 * 16 + ll;
      float val = o[n2][r] / l_r[r];
      attn_out[((size_t)b * NS + q) * ND + h * HD + d] = f2bf(val);
    }
  }
}

// ---------------- proj GEMM: attn @ WprojT + bproj -> out fp32 ----------------

__global__ __launch_bounds__(256) void proj_gemm(const unsigned short* __restrict__ abf,
                                                 const unsigned short* __restrict__ WT,
                                                 const float* __restrict__ bias,
                                                 float* __restrict__ out) {
  __shared__ __align__(16) unsigned short As[128 * LDK];
  __shared__ __align__(16) unsigned short Bs[128 * LDK];
  int m0 = blockIdx.y * 128, n0 = blockIdx.x * 128;
  f32x4 acc[4][4];
#pragma unroll
  for (int m = 0; m < 4; m++)
#pragma unroll
    for (int n = 0; n < 4; n++) acc[m][n] = (f32x4){0.f, 0.f, 0.f, 0.f};

  gemm_mainloop(abf, WT, ND, m0, n0, As, Bs, acc);

  int tid = threadIdx.x, lane = tid & 63, wid = tid >> 6;
  int wr = wid >> 1, wc = wid & 1;
  int ll = lane & 15, lh = lane >> 4;
#pragma unroll
  for (int nf = 0; nf < 4; nf++) {
    int col = n0 + wc * 64 + nf * 16 + ll;
    float bv = bias[col];
#pragma unroll
    for (int mf = 0; mf < 4; mf++) {
#pragma unroll
      for (int r = 0; r < 4; r++) {
        int m = m0 + wr * 64 + mf * 16 + lh * 4 + r;
        out[(size_t)m * ND + col] = acc[mf][nf][r] + bv;
      }
    }
  }
}

// ---------------- launch ----------------

extern "C" void kernel_launch(void* const* d_in, const int* in_sizes, int n_in,
                              void* d_out, int out_size, void* d_ws, size_t ws_size,
                              hipStream_t stream) {
  const float* x = (const float*)d_in[0];
  const float* Wqkv = (const float*)d_in[1];
  const float* bqkv = (const float*)d_in[2];
  const float* Wproj = (const float*)d_in[3];
  const float* bproj = (const float*)d_in[4];
  float* out = (float*)d_out;

  char* ws = (char*)d_ws;
  const size_t SZ_X = (size_t)NB * NS * ND * 2;        // 12,582,912
  const size_t SZ_WQKV = (size_t)ND * 3 * ND * 2;      //  3,538,944
  const size_t SZ_WPROJ = (size_t)ND * ND * 2;         //  1,179,648
  const size_t SZ_HEAD = (size_t)NB * NH * NS * HD * 2;

  unsigned short* xbf = (unsigned short*)(ws);
  unsigned short* wqkvT = (unsigned short*)(ws + SZ_X);
  unsigned short* wprojT = (unsigned short*)(ws + SZ_X + SZ_WQKV);
  unsigned short* qw = (unsigned short*)(ws + SZ_X + SZ_WQKV + SZ_WPROJ);
  unsigned short* kw = qw + (size_t)NB * NH * NS * HD;
  unsigned short* vw = kw + (size_t)NB * NH * NS * HD;
  unsigned short* attn = vw + (size_t)NB * NH * NS * HD;

  (void)in_sizes; (void)n_in; (void)out_size; (void)ws_size; (void)SZ_HEAD;

  // pack: x -> bf16; W -> transposed bf16 [N][K]
  cvt_f32_bf16<<<(NB * NS * ND) / 1024, 256, 0, stream>>>(x, xbf);
  transpose_cvt<<<dim3(3 * ND / 32, ND / 32), 256, 0, stream>>>(Wqkv, wqkvT, ND, 3 * ND);
  transpose_cvt<<<dim3(ND / 32, ND / 32), 256, 0, stream>>>(Wproj, wprojT, ND, ND);

  // qkv = x @ Wqkv + b  -> q/k/v [B,H,S,64] bf16 (q pre-scaled)
  qkv_gemm<<<dim3(3 * ND / 128, NB * NS / 128), 256, 0, stream>>>(xbf, wqkvT, bqkv, qw, kw, vw);

  // flash attention -> attn [B,S,D] bf16
  attn_kernel<<<dim3(NS / 64, NH, NB), 256, 0, stream>>>(qw, kw, vw, attn);

  // out = attn @ Wproj + b  (fp32)
  proj_gemm<<<dim3(ND / 128, NB * NS / 128), 256, 0, stream>>>(attn, wprojT, bproj, out);
}

// Round 2
// 181.441 us; speedup vs baseline: 1.1852x; 1.1852x over previous
//
#include <hip/hip_runtime.h>
#include <cstddef>

typedef float f32x4 __attribute__((ext_vector_type(4)));
typedef short s16x4 __attribute__((ext_vector_type(4)));
typedef short s16x8 __attribute__((ext_vector_type(8)));
typedef __bf16 bf16x8 __attribute__((ext_vector_type(8)));

#define NB 8
#define NS 1024
#define ND 768
#define NH 12
#define HD 64

__device__ __forceinline__ unsigned short f2bf(float f) {
  unsigned u = __builtin_bit_cast(unsigned, f);
  u += 0x7fffu + ((u >> 16) & 1u);
  return (unsigned short)(u >> 16);
}

__device__ __forceinline__ f32x4 mfma16(bf16x8 a, bf16x8 b, f32x4 c) {
  return __builtin_amdgcn_mfma_f32_16x16x32_bf16(a, b, c, 0, 0, 0);
}

__device__ __forceinline__ bf16x8 ld8(const unsigned short* p) {
  return *reinterpret_cast<const bf16x8*>(p);
}

// ---------------- pack kernels ----------------

__global__ __launch_bounds__(256) void cvt_f32_bf16(const float* __restrict__ in,
                                                    unsigned short* __restrict__ out) {
  int i = (blockIdx.x * 256 + threadIdx.x) * 4;
  float4 v = *reinterpret_cast<const float4*>(in + i);
  ushort4 o;
  o.x = f2bf(v.x); o.y = f2bf(v.y); o.z = f2bf(v.z); o.w = f2bf(v.w);
  *reinterpret_cast<ushort4*>(out + i) = o;
}

// in: fp32 [R][C] row-major  ->  out: bf16 [C][R]
__global__ __launch_bounds__(256) void transpose_cvt(const float* __restrict__ in,
                                                     unsigned short* __restrict__ out,
                                                     int R, int C) {
  __shared__ float tile[32][33];
  int c0 = blockIdx.x * 32, r0 = blockIdx.y * 32;
  int tx = threadIdx.x & 31, ty = threadIdx.x >> 5;  // 32 x 8
#pragma unroll
  for (int i = 0; i < 32; i += 8)
    tile[ty + i][tx] = in[(size_t)(r0 + ty + i) * C + c0 + tx];
  __syncthreads();
#pragma unroll
  for (int i = 0; i < 32; i += 8)
    out[(size_t)(c0 + ty + i) * R + r0 + tx] = f2bf(tile[tx][ty + i]);
}

// bf16 per-head transpose: vw [bh][1024 s][64 d] -> vt [bh][64 d][1024 s]
__global__ __launch_bounds__(256) void transpose_v(const unsigned short* __restrict__ vw,
                                                   unsigned short* __restrict__ vt) {
  __shared__ unsigned short tile[32][33];
  int bh = blockIdx.z;
  int d0 = blockIdx.x * 32, s0 = blockIdx.y * 32;
  const unsigned short* in = vw + (size_t)bh * NS * HD;
  unsigned short* out = vt + (size_t)bh * HD * NS;
  int tx = threadIdx.x & 31, ty = threadIdx.x >> 5;  // 32 x 8
#pragma unroll
  for (int i = 0; i < 32; i += 8)
    tile[ty + i][tx] = in[(size_t)(s0 + ty + i) * HD + d0 + tx];
  __syncthreads();
#pragma unroll
  for (int i = 0; i < 32; i += 8)
    out[(size_t)(d0 + ty + i) * NS + s0 + tx] = tile[tx][ty + i];
}

// ---------------- GEMM mainloop (A:[M][K] bf16, Bt:[N][K] bf16) ----------------
// 128x128 tile, 4 waves (2x2), each wave 64x64 via 4x4 16x16x32 frags, BK=32.

#define LDK 40  // 32 + 8 pad

__device__ __forceinline__ void gemm_mainloop(const unsigned short* __restrict__ A,
                                              const unsigned short* __restrict__ Bt,
                                              int K, int m0, int n0,
                                              unsigned short* As, unsigned short* Bs,
                                              f32x4 (&acc)[4][4]) {
  int tid = threadIdx.x;
  int lane = tid & 63, wid = tid >> 6;
  int wr = wid >> 1, wc = wid & 1;
  int srow = tid >> 1;          // 0..127
  int koff = (tid & 1) * 16;    // 0 or 16
  int ll = lane & 15, kg = (lane >> 4) * 8;

  for (int kt = 0; kt < K; kt += 32) {
    __syncthreads();
    *(s16x8*)&As[srow * LDK + koff] =
        *(const s16x8*)&A[(size_t)(m0 + srow) * K + kt + koff];
    *(s16x8*)&As[srow * LDK + koff + 8] =
        *(const s16x8*)&A[(size_t)(m0 + srow) * K + kt + koff + 8];
    *(s16x8*)&Bs[srow * LDK + koff] =
        *(const s16x8*)&Bt[(size_t)(n0 + srow) * K + kt + koff];
    *(s16x8*)&Bs[srow * LDK + koff + 8] =
        *(const s16x8*)&Bt[(size_t)(n0 + srow) * K + kt + koff + 8];
    __syncthreads();

    bf16x8 af[4], bfr[4];
#pragma unroll
    for (int m = 0; m < 4; m++) af[m] = ld8(&As[(wr * 64 + m * 16 + ll) * LDK + kg]);
#pragma unroll
    for (int n = 0; n < 4; n++) bfr[n] = ld8(&Bs[(wc * 64 + n * 16 + ll) * LDK + kg]);
#pragma unroll
    for (int m = 0; m < 4; m++)
#pragma unroll
      for (int n = 0; n < 4; n++) acc[m][n] = mfma16(af[m], bfr[n], acc[m][n]);
  }
}

// ---------------- QKV GEMM ----------------

__global__ __launch_bounds__(256) void qkv_gemm(const unsigned short* __restrict__ xbf,
                                                const unsigned short* __restrict__ WT,
                                                const float* __restrict__ bias,
                                                unsigned short* __restrict__ qw,
                                                unsigned short* __restrict__ kw,
                                                unsigned short* __restrict__ vw) {
  __shared__ __align__(16) unsigned short As[128 * LDK];
  __shared__ __align__(16) unsigned short Bs[128 * LDK];
  int m0 = blockIdx.y * 128, n0 = blockIdx.x * 128;
  f32x4 acc[4][4];
#pragma unroll
  for (int m = 0; m < 4; m++)
#pragma unroll
    for (int n = 0; n < 4; n++) acc[m][n] = (f32x4){0.f, 0.f, 0.f, 0.f};

  gemm_mainloop(xbf, WT, ND, m0, n0, As, Bs, acc);

  int tid = threadIdx.x, lane = tid & 63, wid = tid >> 6;
  int wr = wid >> 1, wc = wid & 1;
  int ll = lane & 15, lh = lane >> 4;
#pragma unroll
  for (int nf = 0; nf < 4; nf++) {
    int col = n0 + wc * 64 + nf * 16 + ll;
    float bv = bias[col];
    int which = col / ND;
    int w2 = col - which * ND;
    int h = w2 >> 6, d = w2 & 63;
#pragma unroll
    for (int mf = 0; mf < 4; mf++) {
#pragma unroll
      for (int r = 0; r < 4; r++) {
        int m = m0 + wr * 64 + mf * 16 + lh * 4 + r;
        int b = m >> 10, s = m & 1023;
        float v = acc[mf][nf][r] + bv;
        size_t idx = (((size_t)b * NH + h) * NS + s) * HD + d;
        if (which == 0)
          qw[idx] = f2bf(v * 0.125f);
        else if (which == 1)
          kw[idx] = f2bf(v);
        else
          vw[idx] = f2bf(v);
      }
    }
  }
}

// ---------------- flash attention: QBLK=128, 8 waves, swapped QK^T ----------------

#define LP 88  // LDS row stride (shorts): 176B, 16B-aligned, conflict-free b128 phases

__global__ __launch_bounds__(512) void attn_kernel(const unsigned short* __restrict__ qw,
                                                   const unsigned short* __restrict__ kw,
                                                   const unsigned short* __restrict__ vt,
                                                   unsigned short* __restrict__ attn_out) {
  int qt = (int)gridDim.x - 1 - (int)blockIdx.x;  // heavy tiles dispatch first
  int h = blockIdx.y, b = blockIdx.z;
  __shared__ __align__(16) unsigned short Ks[64 * LP];
  __shared__ __align__(16) unsigned short Vs[64 * LP];
  __shared__ __align__(16) unsigned short Ps[8][16 * LP];

  int tid = threadIdx.x, lane = tid & 63, wid = tid >> 6;
  int ll = lane & 15, lh = lane >> 4;
  int q0 = qt * 128;
  const size_t bh = ((size_t)b * NH + h) * NS * HD;

  // Q fragments (B-operand of swapped QK): b[i] = Q[q0+wid*16+ll][lh*8+i (+32)]
  int qrow = q0 + wid * 16 + ll;
  bf16x8 qf0 = ld8(&qw[bh + (size_t)qrow * HD + lh * 8]);
  bf16x8 qf1 = ld8(&qw[bh + (size_t)qrow * HD + 32 + lh * 8]);

  f32x4 o[4];
#pragma unroll
  for (int n = 0; n < 4; n++) o[n] = (f32x4){0.f, 0.f, 0.f, 0.f};
  float m_r = -1e30f, l_r = 0.f;

  // staging: 512 threads x 16B = one 64x64 bf16 tile per instruction
  int srow = tid >> 3, sc = (tid & 7) * 8;
  const unsigned short* ksrc = kw + bh + (size_t)srow * HD + sc;
  const unsigned short* vsrc = vt + bh + (size_t)srow * NS + sc;
  unsigned short* kdst = &Ks[srow * LP + sc];
  unsigned short* vdst = &Vs[srow * LP + sc];

  int qmaxw = q0 + wid * 16 + 15;  // wave's highest q row
  int jend = q0 + 128;
  unsigned short* pw = &Ps[wid][ll * LP];

  for (int j0 = 0; j0 < jend; j0 += 64) {
    __syncthreads();
    *(s16x8*)kdst = *(const s16x8*)(ksrc + (size_t)j0 * HD);
    *(s16x8*)vdst = *(const s16x8*)(vsrc + j0);
    __syncthreads();

    if (j0 <= qmaxw) {  // wave-uniform: skip fully-masked tiles
      // S^T = K Q^T : sa[n][r] = S[j=j0+n*16+lh*4+r][q=q0+wid*16+ll]
      f32x4 sa[4];
#pragma unroll
      for (int n = 0; n < 4; n++) {
        bf16x8 kf0 = ld8(&Ks[(n * 16 + ll) * LP + lh * 8]);
        bf16x8 kf1 = ld8(&Ks[(n * 16 + ll) * LP + 32 + lh * 8]);
        sa[n] = mfma16(kf0, qf0, (f32x4){0.f, 0.f, 0.f, 0.f});
        sa[n] = mfma16(kf1, qf1, sa[n]);
      }

      // causal mask (j > q)
      int qme = q0 + wid * 16 + ll;
      if (j0 + 63 > q0 + wid * 16) {
#pragma unroll
        for (int n = 0; n < 4; n++)
#pragma unroll
          for (int r = 0; r < 4; r++)
            if (j0 + n * 16 + lh * 4 + r > qme) sa[n][r] = -1e30f;
      }

      // online softmax: each lane owns one q column (16 j values local)
      float t0 = fmaxf(fmaxf(sa[0][0], sa[0][1]), fmaxf(sa[0][2], sa[0][3]));
      float t1 = fmaxf(fmaxf(sa[1][0], sa[1][1]), fmaxf(sa[1][2], sa[1][3]));
      float t2 = fmaxf(fmaxf(sa[2][0], sa[2][1]), fmaxf(sa[2][2], sa[2][3]));
      float t3 = fmaxf(fmaxf(sa[3][0], sa[3][1]), fmaxf(sa[3][2], sa[3][3]));
      float tmax = fmaxf(fmaxf(t0, t1), fmaxf(t2, t3));
      tmax = fmaxf(tmax, __shfl_xor(tmax, 16));
      tmax = fmaxf(tmax, __shfl_xor(tmax, 32));
      float mnew = fmaxf(m_r, tmax);
      float alpha = __expf(m_r - mnew);
      m_r = mnew;

      float p[4][4];
      float ssum = 0.f;
#pragma unroll
      for (int n = 0; n < 4; n++)
#pragma unroll
        for (int r = 0; r < 4; r++) {
          p[n][r] = __expf(sa[n][r] - mnew);
          ssum += p[n][r];
        }
      ssum += __shfl_xor(ssum, 16);
      ssum += __shfl_xor(ssum, 32);
      l_r = alpha * l_r + ssum;

      // broadcast alpha to O-row owners and rescale O
      float ab0 = __shfl(alpha, lh * 4 + 0);
      float ab1 = __shfl(alpha, lh * 4 + 1);
      float ab2 = __shfl(alpha, lh * 4 + 2);
      float ab3 = __shfl(alpha, lh * 4 + 3);
#pragma unroll
      for (int n2 = 0; n2 < 4; n2++) {
        o[n2][0] *= ab0; o[n2][1] *= ab1; o[n2][2] *= ab2; o[n2][3] *= ab3;
      }

      // pack P^T -> Ps[q=ll][k] (wave-private, no barrier)
#pragma unroll
      for (int n = 0; n < 4; n++) {
        s16x4 pk;
        pk[0] = (short)f2bf(p[n][0]);
        pk[1] = (short)f2bf(p[n][1]);
        pk[2] = (short)f2bf(p[n][2]);
        pk[3] = (short)f2bf(p[n][3]);
        *(s16x4*)&pw[n * 16 + lh * 4] = pk;
      }

      // O += P V : A-frag = P[q=ll][k], B-frag = Vt[d=n2*16+ll][k]
#pragma unroll
      for (int c = 0; c < 2; c++) {
        bf16x8 pf = ld8(&pw[c * 32 + lh * 8]);
#pragma unroll
        for (int n2 = 0; n2 < 4; n2++) {
          bf16x8 vf = ld8(&Vs[(n2 * 16 + ll) * LP + c * 32 + lh * 8]);
          o[n2] = mfma16(pf, vf, o[n2]);
        }
      }
    }
  }

  // epilogue: normalize + store merged heads [B,S,D]
  float lrec = 1.0f / l_r;
  float lb0 = __shfl(lrec, lh * 4 + 0);
  float lb1 = __shfl(lrec, lh * 4 + 1);
  float lb2 = __shfl(lrec, lh * 4 + 2);
  float lb3 = __shfl(lrec, lh * 4 + 3);
#pragma unroll
  for (int n2 = 0; n2 < 4; n2++) {
    int d = n2 * 16 + ll;
    int qb = q0 + wid * 16 + lh * 4;
    attn_out[((size_t)b * NS + qb + 0) * ND + h * HD + d] = f2bf(o[n2][0] * lb0);
    attn_out[((size_t)b * NS + qb + 1) * ND + h * HD + d] = f2bf(o[n2][1] * lb1);
    attn_out[((size_t)b * NS + qb + 2) * ND + h * HD + d] = f2bf(o[n2][2] * lb2);
    attn_out[((size_t)b * NS + qb + 3) * ND + h * HD + d] = f2bf(o[n2][3] * lb3);
  }
}

// ---------------- proj GEMM ----------------

__global__ __launch_bounds__(256) void proj_gemm(const unsigned short* __restrict__ abf,
                                                 const unsigned short* __restrict__ WT,
                                                 const float* __restrict__ bias,
                                                 float* __restrict__ out) {
  __shared__ __align__(16) unsigned short As[128 * LDK];
  __shared__ __align__(16) unsigned short Bs[128 * LDK];
  int m0 = blockIdx.y * 128, n0 = blockIdx.x * 128;
  f32x4 acc[4][4];
#pragma unroll
  for (int m = 0; m < 4; m++)
#pragma unroll
    for (int n = 0; n < 4; n++) acc[m][n] = (f32x4){0.f, 0.f, 0.f, 0.f};

  gemm_mainloop(abf, WT, ND, m0, n0, As, Bs, acc);

  int tid = threadIdx.x, lane = tid & 63, wid = tid >> 6;
  int wr = wid >> 1, wc = wid & 1;
  int ll = lane & 15, lh = lane >> 4;
#pragma unroll
  for (int nf = 0; nf < 4; nf++) {
    int col = n0 + wc * 64 + nf * 16 + ll;
    float bv = bias[col];
#pragma unroll
    for (int mf = 0; mf < 4; mf++) {
#pragma unroll
      for (int r = 0; r < 4; r++) {
        int m = m0 + wr * 64 + mf * 16 + lh * 4 + r;
        out[(size_t)m * ND + col] = acc[mf][nf][r] + bv;
      }
    }
  }
}

// ---------------- launch ----------------

extern "C" void kernel_launch(void* const* d_in, const int* in_sizes, int n_in,
                              void* d_out, int out_size, void* d_ws, size_t ws_size,
                              hipStream_t stream) {
  const float* x = (const float*)d_in[0];
  const float* Wqkv = (const float*)d_in[1];
  const float* bqkv = (const float*)d_in[2];
  const float* Wproj = (const float*)d_in[3];
  const float* bproj = (const float*)d_in[4];
  float* out = (float*)d_out;

  char* ws = (char*)d_ws;
  const size_t SZ_X = (size_t)NB * NS * ND * 2;
  const size_t SZ_WQKV = (size_t)ND * 3 * ND * 2;
  const size_t SZ_WPROJ = (size_t)ND * ND * 2;
  const size_t SZ_HEAD = (size_t)NB * NH * NS * HD;  // elements

  unsigned short* xbf = (unsigned short*)(ws);
  unsigned short* wqkvT = (unsigned short*)(ws + SZ_X);
  unsigned short* wprojT = (unsigned short*)(ws + SZ_X + SZ_WQKV);
  unsigned short* qw = (unsigned short*)(ws + SZ_X + SZ_WQKV + SZ_WPROJ);
  unsigned short* kw = qw + SZ_HEAD;
  unsigned short* vw = kw + SZ_HEAD;
  unsigned short* attn = vw + SZ_HEAD;
  unsigned short* vtb = xbf;  // reuse x's slot: x consumed by qkv_gemm before transpose_v

  (void)in_sizes; (void)n_in; (void)out_size; (void)ws_size;

  cvt_f32_bf16<<<(NB * NS * ND) / 1024, 256, 0, stream>>>(x, xbf);
  transpose_cvt<<<dim3(3 * ND / 32, ND / 32), 256, 0, stream>>>(Wqkv, wqkvT, ND, 3 * ND);
  transpose_cvt<<<dim3(ND / 32, ND / 32), 256, 0, stream>>>(Wproj, wprojT, ND, ND);

  qkv_gemm<<<dim3(3 * ND / 128, NB * NS / 128), 256, 0, stream>>>(xbf, wqkvT, bqkv, qw, kw, vw);

  transpose_v<<<dim3(HD / 32, NS / 32, NB * NH), 256, 0, stream>>>(vw, vtb);

  attn_kernel<<<dim3(NS / 128, NH, NB), 512, 0, stream>>>(qw, kw, vtb, attn);

  proj_gemm<<<dim3(ND / 128, NB * NS / 128), 256, 0, stream>>>(attn, wprojT, bproj, out);
}

// Round 3
// 172.897 us; speedup vs baseline: 1.2438x; 1.0494x over previous
//
#include <hip/hip_runtime.h>
#include <cstddef>

typedef float f32x4 __attribute__((ext_vector_type(4)));
typedef short s16x4 __attribute__((ext_vector_type(4)));
typedef short s16x8 __attribute__((ext_vector_type(8)));
typedef __bf16 bf16x8 __attribute__((ext_vector_type(8)));

#define NB 8
#define NS 1024
#define ND 768
#define NH 12
#define HD 64

__device__ __forceinline__ unsigned short f2bf(float f) {
  unsigned u = __builtin_bit_cast(unsigned, f);
  u += 0x7fffu + ((u >> 16) & 1u);
  return (unsigned short)(u >> 16);
}

__device__ __forceinline__ f32x4 mfma16(bf16x8 a, bf16x8 b, f32x4 c) {
  return __builtin_amdgcn_mfma_f32_16x16x32_bf16(a, b, c, 0, 0, 0);
}

__device__ __forceinline__ bf16x8 ld8(const unsigned short* p) {
  return *reinterpret_cast<const bf16x8*>(p);
}

// async global->LDS, 16B per lane, wave-uniform LDS base + lane*16 (m97 pattern)
__device__ __forceinline__ void gload16(unsigned short* lds_dst, const unsigned short* gsrc) {
  __builtin_amdgcn_global_load_lds(
      (const __attribute__((address_space(1))) unsigned int*)gsrc,
      (__attribute__((address_space(3))) unsigned int*)lds_dst, 16, 0, 0);
}

// ---------------- pack kernels ----------------

__global__ __launch_bounds__(256) void cvt_f32_bf16(const float* __restrict__ in,
                                                    unsigned short* __restrict__ out) {
  int i = (blockIdx.x * 256 + threadIdx.x) * 4;
  float4 v = *reinterpret_cast<const float4*>(in + i);
  ushort4 o;
  o.x = f2bf(v.x); o.y = f2bf(v.y); o.z = f2bf(v.z); o.w = f2bf(v.w);
  *reinterpret_cast<ushort4*>(out + i) = o;
}

// in: fp32 [R][C] row-major  ->  out: bf16 [C][R]
__global__ __launch_bounds__(256) void transpose_cvt(const float* __restrict__ in,
                                                     unsigned short* __restrict__ out,
                                                     int R, int C) {
  __shared__ float tile[32][33];
  int c0 = blockIdx.x * 32, r0 = blockIdx.y * 32;
  int tx = threadIdx.x & 31, ty = threadIdx.x >> 5;  // 32 x 8
#pragma unroll
  for (int i = 0; i < 32; i += 8)
    tile[ty + i][tx] = in[(size_t)(r0 + ty + i) * C + c0 + tx];
  __syncthreads();
#pragma unroll
  for (int i = 0; i < 32; i += 8)
    out[(size_t)(c0 + ty + i) * R + r0 + tx] = f2bf(tile[tx][ty + i]);
}

// bf16 per-head transpose: vw [bh][1024 s][64 d] -> vt [bh][64 d][1024 s]
__global__ __launch_bounds__(256) void transpose_v(const unsigned short* __restrict__ vw,
                                                   unsigned short* __restrict__ vt) {
  __shared__ unsigned short tile[32][33];
  int bh = blockIdx.z;
  int d0 = blockIdx.x * 32, s0 = blockIdx.y * 32;
  const unsigned short* in = vw + (size_t)bh * NS * HD;
  unsigned short* out = vt + (size_t)bh * HD * NS;
  int tx = threadIdx.x & 31, ty = threadIdx.x >> 5;  // 32 x 8
#pragma unroll
  for (int i = 0; i < 32; i += 8)
    tile[ty + i][tx] = in[(size_t)(s0 + ty + i) * HD + d0 + tx];
  __syncthreads();
#pragma unroll
  for (int i = 0; i < 32; i += 8)
    out[(size_t)(d0 + ty + i) * NS + s0 + tx] = tile[tx][ty + i];
}

// ---------------- GEMM mainloop, m97 structure ----------------
// A:[M][K] bf16, Bt:[N][K] bf16. 128x128 tile, BK=64, 4 waves (2x2),
// global_load_lds width-16 staging into linear LDS [128][64].

__device__ __forceinline__ void gemm_mainloop(const unsigned short* __restrict__ A,
                                              const unsigned short* __restrict__ Bt,
                                              int K, int m0, int n0,
                                              unsigned short* As, unsigned short* Bs,
                                              f32x4 (&acc)[4][4]) {
  int tid = threadIdx.x;
  int lane = tid & 63, wid = tid >> 6;
  int wr = wid >> 1, wc = wid & 1;
  int ll = lane & 15, lh = lane >> 4;

  // staging: wave w owns rows [w*32, w*32+32); issue i covers 8 rows (64 lanes x 16B)
  int lrow = wid * 32 + (lane >> 3);
  int lcol = (lane & 7) * 8;
  const unsigned short* asrc = A + (size_t)(m0 + lrow) * K + lcol;
  const unsigned short* bsrc = Bt + (size_t)(n0 + lrow) * K + lcol;
  unsigned short* adst = As + wid * 32 * 64;  // wave-uniform base
  unsigned short* bdst = Bs + wid * 32 * 64;

  for (int kt = 0; kt < K; kt += 64) {
#pragma unroll
    for (int i = 0; i < 4; i++) {
      gload16(adst + i * 8 * 64, asrc + (size_t)i * 8 * K + kt);
      gload16(bdst + i * 8 * 64, bsrc + (size_t)i * 8 * K + kt);
    }
    __syncthreads();  // drains vmcnt: staging complete

#pragma unroll
    for (int c = 0; c < 2; c++) {
      bf16x8 af[4], bg[4];
#pragma unroll
      for (int m = 0; m < 4; m++)
        af[m] = ld8(&As[(wr * 64 + m * 16 + ll) * 64 + c * 32 + lh * 8]);
#pragma unroll
      for (int n = 0; n < 4; n++)
        bg[n] = ld8(&Bs[(wc * 64 + n * 16 + ll) * 64 + c * 32 + lh * 8]);
#pragma unroll
      for (int m = 0; m < 4; m++)
#pragma unroll
        for (int n = 0; n < 4; n++) acc[m][n] = mfma16(af[m], bg[n], acc[m][n]);
    }
    __syncthreads();  // all reads done before next-tile overwrite
  }
}

// ---------------- QKV GEMM ----------------

__global__ __launch_bounds__(256) void qkv_gemm(const unsigned short* __restrict__ xbf,
                                                const unsigned short* __restrict__ WT,
                                                const float* __restrict__ bias,
                                                unsigned short* __restrict__ qw,
                                                unsigned short* __restrict__ kw,
                                                unsigned short* __restrict__ vw) {
  __shared__ __align__(16) unsigned short As[128 * 64];
  __shared__ __align__(16) unsigned short Bs[128 * 64];
  int m0 = blockIdx.y * 128, n0 = blockIdx.x * 128;
  f32x4 acc[4][4];
#pragma unroll
  for (int m = 0; m < 4; m++)
#pragma unroll
    for (int n = 0; n < 4; n++) acc[m][n] = (f32x4){0.f, 0.f, 0.f, 0.f};

  gemm_mainloop(xbf, WT, ND, m0, n0, As, Bs, acc);

  int tid = threadIdx.x, lane = tid & 63, wid = tid >> 6;
  int wr = wid >> 1, wc = wid & 1;
  int ll = lane & 15, lh = lane >> 4;
#pragma unroll
  for (int nf = 0; nf < 4; nf++) {
    int col = n0 + wc * 64 + nf * 16 + ll;
    float bv = bias[col];
    int which = col / ND;
    int w2 = col - which * ND;
    int h = w2 >> 6, d = w2 & 63;
#pragma unroll
    for (int mf = 0; mf < 4; mf++) {
#pragma unroll
      for (int r = 0; r < 4; r++) {
        int m = m0 + wr * 64 + mf * 16 + lh * 4 + r;
        int b = m >> 10, s = m & 1023;
        float v = acc[mf][nf][r] + bv;
        size_t idx = (((size_t)b * NH + h) * NS + s) * HD + d;
        if (which == 0)
          qw[idx] = f2bf(v * 0.125f);
        else if (which == 1)
          kw[idx] = f2bf(v);
        else
          vw[idx] = f2bf(v);
      }
    }
  }
}

// ---------------- flash attention: QBLK=128, 8 waves, swapped QK^T ----------------

#define LP 88  // LDS row stride (shorts): 176B, 16B-aligned

__global__ __launch_bounds__(512) void attn_kernel(const unsigned short* __restrict__ qw,
                                                   const unsigned short* __restrict__ kw,
                                                   const unsigned short* __restrict__ vt,
                                                   unsigned short* __restrict__ attn_out) {
  int qt = (int)gridDim.x - 1 - (int)blockIdx.x;  // heavy tiles dispatch first
  int h = blockIdx.y, b = blockIdx.z;
  __shared__ __align__(16) unsigned short Ks[64 * LP];
  __shared__ __align__(16) unsigned short Vs[64 * LP];
  __shared__ __align__(16) unsigned short Ps[8][16 * LP];

  int tid = threadIdx.x, lane = tid & 63, wid = tid >> 6;
  int ll = lane & 15, lh = lane >> 4;
  int q0 = qt * 128;
  const size_t bh = ((size_t)b * NH + h) * NS * HD;

  int qrow = q0 + wid * 16 + ll;
  bf16x8 qf0 = ld8(&qw[bh + (size_t)qrow * HD + lh * 8]);
  bf16x8 qf1 = ld8(&qw[bh + (size_t)qrow * HD + 32 + lh * 8]);

  f32x4 o[4];
#pragma unroll
  for (int n = 0; n < 4; n++) o[n] = (f32x4){0.f, 0.f, 0.f, 0.f};
  float m_r = -1e30f, l_r = 0.f;

  int srow = tid >> 3, sc = (tid & 7) * 8;
  const unsigned short* ksrc = kw + bh + (size_t)srow * HD + sc;
  const unsigned short* vsrc = vt + bh + (size_t)srow * NS + sc;
  unsigned short* kdst = &Ks[srow * LP + sc];
  unsigned short* vdst = &Vs[srow * LP + sc];

  int qmaxw = q0 + wid * 16 + 15;
  int jend = q0 + 128;
  unsigned short* pw = &Ps[wid][ll * LP];

  for (int j0 = 0; j0 < jend; j0 += 64) {
    __syncthreads();
    *(s16x8*)kdst = *(const s16x8*)(ksrc + (size_t)j0 * HD);
    *(s16x8*)vdst = *(const s16x8*)(vsrc + j0);
    __syncthreads();

    if (j0 <= qmaxw) {
      f32x4 sa[4];
#pragma unroll
      for (int n = 0; n < 4; n++) {
        bf16x8 kf0 = ld8(&Ks[(n * 16 + ll) * LP + lh * 8]);
        bf16x8 kf1 = ld8(&Ks[(n * 16 + ll) * LP + 32 + lh * 8]);
        sa[n] = mfma16(kf0, qf0, (f32x4){0.f, 0.f, 0.f, 0.f});
        sa[n] = mfma16(kf1, qf1, sa[n]);
      }

      int qme = q0 + wid * 16 + ll;
      if (j0 + 63 > q0 + wid * 16) {
#pragma unroll
        for (int n = 0; n < 4; n++)
#pragma unroll
          for (int r = 0; r < 4; r++)
            if (j0 + n * 16 + lh * 4 + r > qme) sa[n][r] = -1e30f;
      }

      float t0 = fmaxf(fmaxf(sa[0][0], sa[0][1]), fmaxf(sa[0][2], sa[0][3]));
      float t1 = fmaxf(fmaxf(sa[1][0], sa[1][1]), fmaxf(sa[1][2], sa[1][3]));
      float t2 = fmaxf(fmaxf(sa[2][0], sa[2][1]), fmaxf(sa[2][2], sa[2][3]));
      float t3 = fmaxf(fmaxf(sa[3][0], sa[3][1]), fmaxf(sa[3][2], sa[3][3]));
      float tmax = fmaxf(fmaxf(t0, t1), fmaxf(t2, t3));
      tmax = fmaxf(tmax, __shfl_xor(tmax, 16));
      tmax = fmaxf(tmax, __shfl_xor(tmax, 32));
      float mnew = fmaxf(m_r, tmax);
      float alpha = __expf(m_r - mnew);
      m_r = mnew;

      float p[4][4];
      float ssum = 0.f;
#pragma unroll
      for (int n = 0; n < 4; n++)
#pragma unroll
        for (int r = 0; r < 4; r++) {
          p[n][r] = __expf(sa[n][r] - mnew);
          ssum += p[n][r];
        }
      ssum += __shfl_xor(ssum, 16);
      ssum += __shfl_xor(ssum, 32);
      l_r = alpha * l_r + ssum;

      float ab0 = __shfl(alpha, lh * 4 + 0);
      float ab1 = __shfl(alpha, lh * 4 + 1);
      float ab2 = __shfl(alpha, lh * 4 + 2);
      float ab3 = __shfl(alpha, lh * 4 + 3);
#pragma unroll
      for (int n2 = 0; n2 < 4; n2++) {
        o[n2][0] *= ab0; o[n2][1] *= ab1; o[n2][2] *= ab2; o[n2][3] *= ab3;
      }

#pragma unroll
      for (int n = 0; n < 4; n++) {
        s16x4 pk;
        pk[0] = (short)f2bf(p[n][0]);
        pk[1] = (short)f2bf(p[n][1]);
        pk[2] = (short)f2bf(p[n][2]);
        pk[3] = (short)f2bf(p[n][3]);
        *(s16x4*)&pw[n * 16 + lh * 4] = pk;
      }

#pragma unroll
      for (int c = 0; c < 2; c++) {
        bf16x8 pf = ld8(&pw[c * 32 + lh * 8]);
#pragma unroll
        for (int n2 = 0; n2 < 4; n2++) {
          bf16x8 vf = ld8(&Vs[(n2 * 16 + ll) * LP + c * 32 + lh * 8]);
          o[n2] = mfma16(pf, vf, o[n2]);
        }
      }
    }
  }

  float lrec = 1.0f / l_r;
  float lb0 = __shfl(lrec, lh * 4 + 0);
  float lb1 = __shfl(lrec, lh * 4 + 1);
  float lb2 = __shfl(lrec, lh * 4 + 2);
  float lb3 = __shfl(lrec, lh * 4 + 3);
#pragma unroll
  for (int n2 = 0; n2 < 4; n2++) {
    int d = n2 * 16 + ll;
    int qb = q0 + wid * 16 + lh * 4;
    attn_out[((size_t)b * NS + qb + 0) * ND + h * HD + d] = f2bf(o[n2][0] * lb0);
    attn_out[((size_t)b * NS + qb + 1) * ND + h * HD + d] = f2bf(o[n2][1] * lb1);
    attn_out[((size_t)b * NS + qb + 2) * ND + h * HD + d] = f2bf(o[n2][2] * lb2);
    attn_out[((size_t)b * NS + qb + 3) * ND + h * HD + d] = f2bf(o[n2][3] * lb3);
  }
}

// ---------------- proj GEMM ----------------

__global__ __launch_bounds__(256) void proj_gemm(const unsigned short* __restrict__ abf,
                                                 const unsigned short* __restrict__ WT,
                                                 const float* __restrict__ bias,
                                                 float* __restrict__ out) {
  __shared__ __align__(16) unsigned short As[128 * 64];
  __shared__ __align__(16) unsigned short Bs[128 * 64];
  int m0 = blockIdx.y * 128, n0 = blockIdx.x * 128;
  f32x4 acc[4][4];
#pragma unroll
  for (int m = 0; m < 4; m++)
#pragma unroll
    for (int n = 0; n < 4; n++) acc[m][n] = (f32x4){0.f, 0.f, 0.f, 0.f};

  gemm_mainloop(abf, WT, ND, m0, n0, As, Bs, acc);

  int tid = threadIdx.x, lane = tid & 63, wid = tid >> 6;
  int wr = wid >> 1, wc = wid & 1;
  int ll = lane & 15, lh = lane >> 4;
#pragma unroll
  for (int nf = 0; nf < 4; nf++) {
    int col = n0 + wc * 64 + nf * 16 + ll;
    float bv = bias[col];
#pragma unroll
    for (int mf = 0; mf < 4; mf++) {
#pragma unroll
      for (int r = 0; r < 4; r++) {
        int m = m0 + wr * 64 + mf * 16 + lh * 4 + r;
        out[(size_t)m * ND + col] = acc[mf][nf][r] + bv;
      }
    }
  }
}

// ---------------- launch ----------------

extern "C" void kernel_launch(void* const* d_in, const int* in_sizes, int n_in,
                              void* d_out, int out_size, void* d_ws, size_t ws_size,
                              hipStream_t stream) {
  const float* x = (const float*)d_in[0];
  const float* Wqkv = (const float*)d_in[1];
  const float* bqkv = (const float*)d_in[2];
  const float* Wproj = (const float*)d_in[3];
  const float* bproj = (const float*)d_in[4];
  float* out = (float*)d_out;

  char* ws = (char*)d_ws;
  const size_t SZ_X = (size_t)NB * NS * ND * 2;
  const size_t SZ_WQKV = (size_t)ND * 3 * ND * 2;
  const size_t SZ_WPROJ = (size_t)ND * ND * 2;
  const size_t SZ_HEAD = (size_t)NB * NH * NS * HD;  // elements

  unsigned short* xbf = (unsigned short*)(ws);
  unsigned short* wqkvT = (unsigned short*)(ws + SZ_X);
  unsigned short* wprojT = (unsigned short*)(ws + SZ_X + SZ_WQKV);
  unsigned short* qw = (unsigned short*)(ws + SZ_X + SZ_WQKV + SZ_WPROJ);
  unsigned short* kw = qw + SZ_HEAD;
  unsigned short* vw = kw + SZ_HEAD;
  unsigned short* attn = vw + SZ_HEAD;
  unsigned short* vtb = xbf;  // reuse x's slot: x consumed by qkv_gemm before transpose_v

  (void)in_sizes; (void)n_in; (void)out_size; (void)ws_size;

  cvt_f32_bf16<<<(NB * NS * ND) / 1024, 256, 0, stream>>>(x, xbf);
  transpose_cvt<<<dim3(3 * ND / 32, ND / 32), 256, 0, stream>>>(Wqkv, wqkvT, ND, 3 * ND);
  transpose_cvt<<<dim3(ND / 32, ND / 32), 256, 0, stream>>>(Wproj, wprojT, ND, ND);

  qkv_gemm<<<dim3(3 * ND / 128, NB * NS / 128), 256, 0, stream>>>(xbf, wqkvT, bqkv, qw, kw, vw);

  transpose_v<<<dim3(HD / 32, NS / 32, NB * NH), 256, 0, stream>>>(vw, vtb);

  attn_kernel<<<dim3(NS / 128, NH, NB), 512, 0, stream>>>(qw, kw, vtb, attn);

  proj_gemm<<<dim3(ND / 128, NB * NS / 128), 256, 0, stream>>>(attn, wprojT, bproj, out);
}